// Round 1
// baseline (5813.517 us; speedup 1.0000x reference)
//
#include <hip/hip_runtime.h>

#define S_ 50
#define B_ 64
#define T_ 32
#define E_ 512
#define H_ 1024
#define C_ 1024
#define V_ 32000
#define TS_ 31            // T-1 steps
#define NR_ 1984          // TS_*B_ rows

typedef __attribute__((ext_vector_type(8))) short s8v;   // 8 x bf16 bits
typedef __attribute__((ext_vector_type(4))) float f4v;   // MFMA acc

static __device__ __forceinline__ float b2f(ushort u) {
  unsigned x = ((unsigned)u) << 16; float f; __builtin_memcpy(&f, &x, 4); return f;
}
static __device__ __forceinline__ ushort f2b(float f) {
  unsigned x; __builtin_memcpy(&x, &f, 4);
  x = x + 0x7FFFu + ((x >> 16) & 1u);
  return (ushort)(x >> 16);
}
static __device__ __forceinline__ float sigm(float x) { return 1.f / (1.f + __expf(-x)); }

// A-frag: lane holds row (l&15), k = kb + 8*(l>>4) + j   (16B contiguous load)
// B-frag: same pattern on the (N x K) row-major weight => B[k][n], n = l&15.
static __device__ __forceinline__ s8v ldfrag(const ushort* base, int ld, int row0, int kb, int lane) {
  const ushort* p = base + (size_t)(row0 + (lane & 15)) * ld + (kb + ((lane >> 4) << 3));
  return *reinterpret_cast<const s8v*>(p);
}

// ---------------- conversions / gathers ----------------

__global__ void k_convert(const float* __restrict__ s, ushort* __restrict__ d, int n) {
  int i = (blockIdx.x * 256 + threadIdx.x) * 4;
  if (i >= n) return;
  float4 v = *reinterpret_cast<const float4*>(s + i);
  ushort4 o; o.x = f2b(v.x); o.y = f2b(v.y); o.z = f2b(v.z); o.w = f2b(v.w);
  *reinterpret_cast<ushort4*>(d + i) = o;
}

// W_c2h (H x C) -> bf16 transposed (C x H)
__global__ void k_convert_T(const float* __restrict__ s, ushort* __restrict__ d) {
  int gid = blockIdx.x * 256 + threadIdx.x;          // 1M threads
  int h = gid & 1023, c = gid >> 10;
  d[(size_t)c * 1024 + h] = f2b(s[(size_t)h * 1024 + c]);
}

// x_all[i,:] = emb[y[i],:] (0 if y[i]==0), bf16, i in [0,NR_)
__global__ void k_gather(const int* __restrict__ y, const float* __restrict__ emb,
                         ushort* __restrict__ xb) {
  int gid = blockIdx.x * 256 + threadIdx.x;          // NR_*E_/4 threads
  if (gid >= NR_ * (E_ / 4)) return;
  int i = gid >> 7;                // row (E_/4 = 128 quads per row)
  int c = (gid & 127) << 2;
  int idx = y[i];
  float4 v = make_float4(0.f, 0.f, 0.f, 0.f);
  if (idx != 0) v = *reinterpret_cast<const float4*>(emb + (size_t)idx * E_ + c);
  ushort4 o; o.x = f2b(v.x); o.y = f2b(v.y); o.z = f2b(v.z); o.w = f2b(v.w);
  *reinterpret_cast<ushort4*>(xb + (size_t)i * E_ + c) = o;
}

// ---------------- generic GEMM: out[m,n] = sum_k A[m,k]*B[n,k] (+bias) (opt tanh) ----------------
// A: M x K row-major bf16; B: N x K row-major bf16. M%64==0 (grid.y=M/64), N%64==0, K%32==0.
__global__ void gemm_bt(const ushort* __restrict__ A, const ushort* __restrict__ Bm,
                        const float* __restrict__ bias, float* __restrict__ outF,
                        ushort* __restrict__ outB, int M, int N, int K, int act) {
  int l = threadIdx.x & 63, w = threadIdx.x >> 6;
  int m0 = blockIdx.y * 64 + w * 16;
  int n0 = blockIdx.x * 64;
  f4v acc[4] = {{0.f,0.f,0.f,0.f},{0.f,0.f,0.f,0.f},{0.f,0.f,0.f,0.f},{0.f,0.f,0.f,0.f}};
  for (int kb = 0; kb < K; kb += 32) {
    s8v a = ldfrag(A, K, m0, kb, l);
#pragma unroll
    for (int nt = 0; nt < 4; nt++) {
      s8v b = ldfrag(Bm, K, n0 + nt * 16, kb, l);
      acc[nt] = __builtin_amdgcn_mfma_f32_16x16x32_bf16(a, b, acc[nt], 0, 0, 0);
    }
  }
  int rb = (l >> 4) * 2 * 2;  // (l>>4)*4
  int col = l & 15;
#pragma unroll
  for (int nt = 0; nt < 4; nt++) {
    int n = n0 + nt * 16 + col;
    float bv = bias ? bias[n] : 0.f;
#pragma unroll
    for (int i = 0; i < 4; i++) {
      int m = m0 + rb + i;
      float v = acc[nt][i] + bv;
      if (act) v = tanhf(v);
      size_t o = (size_t)m * N + n;
      if (outF) outF[o] = v;
      if (outB) outB[o] = f2b(v);
    }
  }
}

// ---------------- step kernels ----------------

// GRU0: h1 = GRU(x_t, h_prev). gi (x@Wih.T + bih) precomputed (bf16). grid=64 (16-col slices), block=256.
__global__ void k_gru0(const ushort* __restrict__ hpb, const float* __restrict__ hpf,
                       const ushort* __restrict__ Whh, const ushort* __restrict__ gi0t,
                       const float* __restrict__ bhh, float* __restrict__ h1f,
                       ushort* __restrict__ h1b) {
  int l = threadIdx.x & 63, w = threadIdx.x >> 6;
  int j = blockIdx.x * 16;
  int m0 = w * 16;
  f4v aR = {0.f,0.f,0.f,0.f}, aZ = {0.f,0.f,0.f,0.f}, aN = {0.f,0.f,0.f,0.f};
  for (int kb = 0; kb < H_; kb += 32) {
    s8v a = ldfrag(hpb, H_, m0, kb, l);
    s8v bR = ldfrag(Whh, H_, j, kb, l);
    s8v bZ = ldfrag(Whh, H_, H_ + j, kb, l);
    s8v bN = ldfrag(Whh, H_, 2 * H_ + j, kb, l);
    aR = __builtin_amdgcn_mfma_f32_16x16x32_bf16(a, bR, aR, 0, 0, 0);
    aZ = __builtin_amdgcn_mfma_f32_16x16x32_bf16(a, bZ, aZ, 0, 0, 0);
    aN = __builtin_amdgcn_mfma_f32_16x16x32_bf16(a, bN, aN, 0, 0, 0);
  }
  int rb = (l >> 4) * 4, c = j + (l & 15);
#pragma unroll
  for (int i = 0; i < 4; i++) {
    int m = m0 + rb + i;
    const ushort* gi = gi0t + (size_t)m * (3 * H_);
    float gir = b2f(gi[c]), giz = b2f(gi[H_ + c]), gin = b2f(gi[2 * H_ + c]);
    float ghr = aR[i] + bhh[c], ghz = aZ[i] + bhh[H_ + c], ghn = aN[i] + bhh[2 * H_ + c];
    float r = sigm(gir + ghr);
    float zg = sigm(giz + ghz);
    float nn = tanhf(gin + r * ghn);
    float hp = hpf[(size_t)m * H_ + c];
    float h1 = (1.f - zg) * nn + zg * hp;
    h1f[(size_t)m * H_ + c] = h1;
    h1b[(size_t)m * H_ + c] = f2b(h1);
  }
}

// hid = h1@W_h2c.T  and  gh1 = h1@W_hh1.T  (both raw, no bias). grid=256, block=256.
__global__ void k_hidgh1(const ushort* __restrict__ h1b, const ushort* __restrict__ Wh2c,
                         const ushort* __restrict__ Whh1, float* __restrict__ hidf,
                         float* __restrict__ gh1f) {
  int l = threadIdx.x & 63, w = threadIdx.x >> 6;
  int g = blockIdx.x * 16;
  const ushort* Bm; int brow, ldd, dcol; float* dst;
  if (g < C_) { Bm = Wh2c; brow = g; dst = hidf; ldd = C_; dcol = g; }
  else { Bm = Whh1; brow = g - C_; dst = gh1f; ldd = 3 * H_; dcol = g - C_; }
  int m0 = w * 16;
  f4v acc = {0.f,0.f,0.f,0.f};
  for (int kb = 0; kb < H_; kb += 32) {
    s8v a = ldfrag(h1b, H_, m0, kb, l);
    s8v b = ldfrag(Bm, H_, brow, kb, l);
    acc = __builtin_amdgcn_mfma_f32_16x16x32_bf16(a, b, acc, 0, 0, 0);
  }
  int rb = (l >> 4) * 4, c = dcol + (l & 15);
#pragma unroll
  for (int i = 0; i < 4; i++) {
    int m = m0 + rb + i;
    dst[(size_t)m * ldd + c] = acc[i];
  }
}

// attention: scores -> softmax -> z_raw (bf16). grid=64 (one block per batch elem b).
__global__ void k_attn(const ushort* __restrict__ ctxpb, const float* __restrict__ hidf,
                       const float* __restrict__ wmlp, const ushort* __restrict__ ctxb,
                       ushort* __restrict__ zrawb) {
  __shared__ float hs[C_];
  __shared__ float sc[S_];
  __shared__ float al[S_];
  int b = blockIdx.x, tid = threadIdx.x;
  for (int c = tid; c < C_; c += 256) hs[c] = hidf[(size_t)b * C_ + c];
  __syncthreads();
  int w = tid >> 6, l = tid & 63;
  for (int s = w; s < S_; s += 4) {
    const ushort* row = ctxpb + ((size_t)s * B_ + b) * C_;
    float acc = 0.f;
    for (int c = l; c < C_; c += 64) acc += tanhf(b2f(row[c]) + hs[c]) * wmlp[c];
    for (int m = 32; m; m >>= 1) acc += __shfl_xor(acc, m, 64);
    if (l == 0) sc[s] = acc;
  }
  __syncthreads();
  float mx = -1e30f;
  for (int s = 0; s < S_; s++) mx = fmaxf(mx, sc[s]);
  float sm = 0.f;
  for (int s = 0; s < S_; s++) sm += __expf(sc[s] - mx);
  if (tid < S_) al[tid] = __expf(sc[tid] - mx) / sm;
  __syncthreads();
  int c0 = tid * 4;
  float a0 = 0.f, a1 = 0.f, a2 = 0.f, a3 = 0.f;
  for (int s = 0; s < S_; s++) {
    float a = al[s];
    ushort4 cv = *reinterpret_cast<const ushort4*>(ctxb + ((size_t)s * B_ + b) * C_ + c0);
    a0 += a * b2f(cv.x); a1 += a * b2f(cv.y); a2 += a * b2f(cv.z); a3 += a * b2f(cv.w);
  }
  ushort4 o; o.x = f2b(a0); o.y = f2b(a1); o.z = f2b(a2); o.w = f2b(a3);
  *reinterpret_cast<ushort4*>(zrawb + (size_t)b * C_ + c0) = o;
}

// GRU1 via W_comb = W_ih1 @ W_c2h: gi1 = z_raw @ W_comb.T + b_ih1; gh1 precomputed raw.
__global__ void k_gru1(const ushort* __restrict__ zrawb, const ushort* __restrict__ Wcomb,
                       const float* __restrict__ gh1f, const float* __restrict__ bih,
                       const float* __restrict__ bhh, const float* __restrict__ h1f,
                       float* __restrict__ h2f, ushort* __restrict__ h2b) {
  int l = threadIdx.x & 63, w = threadIdx.x >> 6;
  int j = blockIdx.x * 16;
  int m0 = w * 16;
  f4v aR = {0.f,0.f,0.f,0.f}, aZ = {0.f,0.f,0.f,0.f}, aN = {0.f,0.f,0.f,0.f};
  for (int kb = 0; kb < C_; kb += 32) {
    s8v a = ldfrag(zrawb, C_, m0, kb, l);
    s8v bR = ldfrag(Wcomb, C_, j, kb, l);
    s8v bZ = ldfrag(Wcomb, C_, H_ + j, kb, l);
    s8v bN = ldfrag(Wcomb, C_, 2 * H_ + j, kb, l);
    aR = __builtin_amdgcn_mfma_f32_16x16x32_bf16(a, bR, aR, 0, 0, 0);
    aZ = __builtin_amdgcn_mfma_f32_16x16x32_bf16(a, bZ, aZ, 0, 0, 0);
    aN = __builtin_amdgcn_mfma_f32_16x16x32_bf16(a, bN, aN, 0, 0, 0);
  }
  int rb = (l >> 4) * 4, c = j + (l & 15);
#pragma unroll
  for (int i = 0; i < 4; i++) {
    int m = m0 + rb + i;
    float gir = aR[i] + bih[c], giz = aZ[i] + bih[H_ + c], gin = aN[i] + bih[2 * H_ + c];
    const float* gh = gh1f + (size_t)m * (3 * H_);
    float ghr = gh[c] + bhh[c], ghz = gh[H_ + c] + bhh[H_ + c], ghn = gh[2 * H_ + c] + bhh[2 * H_ + c];
    float r = sigm(gir + ghr);
    float zg = sigm(giz + ghz);
    float nn = tanhf(gin + r * ghn);
    float h1 = h1f[(size_t)m * H_ + c];
    float h2 = (1.f - zg) * nn + zg * h1;
    h2f[(size_t)m * H_ + c] = h2;
    h2b[(size_t)m * H_ + c] = f2b(h2);
  }
}

// ---------------- epilogue: streaming LSE over vocab ----------------
// grid (16 chunks of 2000 cols, 16 rowblocks of 128), block=512 (8 waves of 16 rows each).
__global__ void k_lse(const ushort* __restrict__ logitb, const ushort* __restrict__ Wopb,
                      const float* __restrict__ bop, float* __restrict__ part) {
  int l = threadIdx.x & 63, w = threadIdx.x >> 6;
  int r0 = blockIdx.y * 128 + w * 16;
  int c0 = blockIdx.x * 2000;
  f4v mr = {-1e30f, -1e30f, -1e30f, -1e30f};
  f4v sr = {0.f, 0.f, 0.f, 0.f};
  const s8v zf = {0,0,0,0,0,0,0,0};
  int arow = r0 + (l & 15);
  for (int ct = 0; ct < 125; ct++) {
    int n0 = c0 + ct * 16;
    f4v acc = {0.f,0.f,0.f,0.f};
    for (int kb = 0; kb < E_; kb += 32) {
      s8v a = zf;
      if (arow < NR_)
        a = *reinterpret_cast<const s8v*>(logitb + (size_t)arow * E_ + kb + ((l >> 4) << 3));
      s8v b = ldfrag(Wopb, E_, n0, kb, l);
      acc = __builtin_amdgcn_mfma_f32_16x16x32_bf16(a, b, acc, 0, 0, 0);
    }
    float bv = bop[n0 + (l & 15)];
#pragma unroll
    for (int i = 0; i < 4; i++) {
      float v = acc[i] + bv;
      if (v <= mr[i]) {
        sr[i] += __expf(v - mr[i]);
      } else {
        sr[i] = sr[i] * __expf(mr[i] - v) + 1.f;
        mr[i] = v;
      }
    }
  }
  // combine across the 16 lanes sharing each row (l>>4 fixed group)
  for (int sh = 1; sh < 16; sh <<= 1) {
#pragma unroll
    for (int i = 0; i < 4; i++) {
      float om = __shfl_xor(mr[i], sh, 64);
      float os = __shfl_xor(sr[i], sh, 64);
      float mn = fmaxf(mr[i], om);
      sr[i] = sr[i] * __expf(mr[i] - mn) + os * __expf(om - mn);
      mr[i] = mn;
    }
  }
  if ((l & 15) == 0) {
#pragma unroll
    for (int i = 0; i < 4; i++) {
      int row = r0 + (l >> 4) * 4 + i;
      if (row < NR_) {
        size_t o = ((size_t)row * 16 + blockIdx.x) * 2;
        part[o] = mr[i];
        part[o + 1] = sr[i];
      }
    }
  }
}

// per-row: combine chunk partials -> lse; target dot (fp32 W_op); masked nll
__global__ void k_final(const float* __restrict__ part, const ushort* __restrict__ logitb,
                        const float* __restrict__ Wop, const float* __restrict__ bop,
                        const int* __restrict__ y, float* __restrict__ nll) {
  int i = blockIdx.x * 256 + threadIdx.x;
  if (i >= NR_) return;
  float m = -1e30f;
  for (int c = 0; c < 16; c++) m = fmaxf(m, part[((size_t)i * 16 + c) * 2]);
  float s = 0.f;
  for (int c = 0; c < 16; c++) {
    size_t o = ((size_t)i * 16 + c) * 2;
    s += part[o + 1] * __expf(part[o] - m);
  }
  float lse = m + logf(s);
  int tgt = y[i + B_];   // y[(t+1)*B + b] == y[i + 64]
  float v = 0.f;
  if (tgt != 0) {
    const ushort* lr = logitb + (size_t)i * E_;
    const float* wr = Wop + (size_t)tgt * E_;
    float dot = 0.f;
    for (int k = 0; k < E_; k++) dot += b2f(lr[k]) * wr[k];
    dot += bop[tgt];
    v = lse - dot;
  }
  nll[i] = v;
}

__global__ void k_reduce(const float* __restrict__ nll, float* __restrict__ out) {
  __shared__ float sh[256];
  float a = 0.f;
  for (int i = threadIdx.x; i < NR_; i += 256) a += nll[i];
  sh[threadIdx.x] = a;
  __syncthreads();
  for (int s = 128; s; s >>= 1) {
    if (threadIdx.x < s) sh[threadIdx.x] += sh[threadIdx.x + s];
    __syncthreads();
  }
  if (threadIdx.x == 0) out[0] = sh[0];
}

// ---------------- host ----------------

extern "C" void kernel_launch(void* const* d_in, const int* in_sizes, int n_in,
                              void* d_out, int out_size, void* d_ws, size_t ws_size,
                              hipStream_t stream) {
  const float* ctx  = (const float*)d_in[0];
  const int*   y    = (const int*)d_in[1];
  const float* emb  = (const float*)d_in[2];
  const float* Wih0 = (const float*)d_in[3];
  const float* Whh0 = (const float*)d_in[4];
  const float* bih0 = (const float*)d_in[5];
  const float* bhh0 = (const float*)d_in[6];
  const float* Wih1 = (const float*)d_in[7];
  const float* Whh1 = (const float*)d_in[8];
  const float* bih1 = (const float*)d_in[9];
  const float* bhh1 = (const float*)d_in[10];
  const float* Wc2c = (const float*)d_in[11];
  const float* Wh2c = (const float*)d_in[12];
  const float* wmlp = (const float*)d_in[13];
  const float* Wc2h = (const float*)d_in[14];
  const float* Who  = (const float*)d_in[15];
  const float* bho  = (const float*)d_in[16];
  const float* Wop  = (const float*)d_in[17];
  const float* bop  = (const float*)d_in[18];

  char* ws = (char*)d_ws;
  size_t off = 0;
  auto alloc = [&](size_t bytes) { void* p = ws + off; off += (bytes + 255) & ~size_t(255); return p; };

  ushort* ctxb   = (ushort*)alloc((size_t)S_ * B_ * C_ * 2);
  ushort* wih0b  = (ushort*)alloc((size_t)3 * H_ * E_ * 2);
  ushort* whh0b  = (ushort*)alloc((size_t)3 * H_ * H_ * 2);
  ushort* wh2cb  = (ushort*)alloc((size_t)C_ * H_ * 2);
  ushort* wc2hT  = (ushort*)alloc((size_t)C_ * H_ * 2);
  ushort* wih1b  = (ushort*)alloc((size_t)3 * H_ * H_ * 2);
  ushort* whh1b  = (ushort*)alloc((size_t)3 * H_ * H_ * 2);
  ushort* whob   = (ushort*)alloc((size_t)E_ * H_ * 2);
  ushort* wopb   = (ushort*)alloc((size_t)V_ * E_ * 2);
  ushort* wc2cb  = (ushort*)alloc((size_t)C_ * C_ * 2);
  ushort* wcombb = (ushort*)alloc((size_t)3 * H_ * C_ * 2);
  ushort* xb     = (ushort*)alloc((size_t)NR_ * E_ * 2);
  ushort* gi0b   = (ushort*)alloc((size_t)NR_ * 3 * H_ * 2);
  ushort* ctxpb  = (ushort*)alloc((size_t)S_ * B_ * C_ * 2);
  float*  H2f    = (float*)alloc((size_t)TS_ * B_ * H_ * 4);
  ushort* H2b    = (ushort*)alloc((size_t)TS_ * B_ * H_ * 2);
  float*  h0f    = (float*)alloc((size_t)B_ * H_ * 4);
  ushort* h0b    = (ushort*)alloc((size_t)B_ * H_ * 2);
  float*  h1f    = (float*)alloc((size_t)B_ * H_ * 4);
  ushort* h1b    = (ushort*)alloc((size_t)B_ * H_ * 2);
  float*  hidf   = (float*)alloc((size_t)B_ * C_ * 4);
  float*  gh1f   = (float*)alloc((size_t)B_ * 3 * H_ * 4);
  ushort* zrawb  = (ushort*)alloc((size_t)B_ * C_ * 2);
  ushort* logitb = (ushort*)alloc((size_t)NR_ * E_ * 2);
  float*  part   = (float*)alloc((size_t)2048 * 16 * 2 * 4);
  float*  nllb   = (float*)alloc((size_t)2048 * 4);
  (void)ws_size; (void)in_sizes; (void)n_in; (void)out_size;

  // zero initial hidden state (ws is poisoned before timing)
  hipMemsetAsync(h0f, 0, (size_t)B_ * H_ * 4, stream);
  hipMemsetAsync(h0b, 0, (size_t)B_ * H_ * 2, stream);

  auto cgrid = [](int n) { return dim3((unsigned)((n / 4 + 255) / 256)); };
  // fp32 -> bf16 weight/activation conversions
  k_convert<<<cgrid(S_ * B_ * C_), 256, 0, stream>>>(ctx, ctxb, S_ * B_ * C_);
  k_convert<<<cgrid(3 * H_ * E_), 256, 0, stream>>>(Wih0, wih0b, 3 * H_ * E_);
  k_convert<<<cgrid(3 * H_ * H_), 256, 0, stream>>>(Whh0, whh0b, 3 * H_ * H_);
  k_convert<<<cgrid(C_ * H_), 256, 0, stream>>>(Wh2c, wh2cb, C_ * H_);
  k_convert<<<cgrid(3 * H_ * H_), 256, 0, stream>>>(Wih1, wih1b, 3 * H_ * H_);
  k_convert<<<cgrid(3 * H_ * H_), 256, 0, stream>>>(Whh1, whh1b, 3 * H_ * H_);
  k_convert<<<cgrid(E_ * H_), 256, 0, stream>>>(Who, whob, E_ * H_);
  k_convert<<<cgrid(V_ * E_), 256, 0, stream>>>(Wop, wopb, V_ * E_);
  k_convert<<<cgrid(C_ * C_), 256, 0, stream>>>(Wc2c, wc2cb, C_ * C_);
  k_convert_T<<<dim3(4096), 256, 0, stream>>>(Wc2h, wc2hT);

  // embedding gather (padding_idx=0)
  k_gather<<<dim3((NR_ * (E_ / 4) + 255) / 256), 256, 0, stream>>>(y, emb, xb);

  // gi0 for all steps: xb @ Wih0.T + bih0 -> bf16
  gemm_bt<<<dim3(3 * H_ / 64, NR_ / 64), 256, 0, stream>>>(xb, wih0b, bih0, nullptr, gi0b,
                                                           NR_, 3 * H_, E_, 0);
  // ctx_proj: ctx @ Wc2c.T -> bf16
  gemm_bt<<<dim3(C_ / 64, S_ * B_ / 64), 256, 0, stream>>>(ctxb, wc2cb, nullptr, nullptr, ctxpb,
                                                           S_ * B_, C_, C_, 0);
  // W_comb = W_ih1 @ W_c2h  (out[n,c] = sum_h Wih1[n,h]*Wc2hT[c,h]) -> bf16
  gemm_bt<<<dim3(C_ / 64, 3 * H_ / 64), 256, 0, stream>>>(wih1b, wc2hT, nullptr, nullptr, wcombb,
                                                          3 * H_, C_, H_, 0);

  for (int t = 0; t < TS_; t++) {
    const float*  hpf = (t == 0) ? h0f : (H2f + (size_t)(t - 1) * B_ * H_);
    const ushort* hpb = (t == 0) ? h0b : (H2b + (size_t)(t - 1) * B_ * H_);
    k_gru0<<<dim3(H_ / 16), 256, 0, stream>>>(hpb, hpf, whh0b,
                                              gi0b + (size_t)t * B_ * 3 * H_, bhh0, h1f, h1b);
    k_hidgh1<<<dim3((C_ + 3 * H_) / 16), 256, 0, stream>>>(h1b, wh2cb, whh1b, hidf, gh1f);
    k_attn<<<dim3(B_), 256, 0, stream>>>(ctxpb, hidf, wmlp, ctxb, zrawb);
    k_gru1<<<dim3(H_ / 16), 256, 0, stream>>>(zrawb, wcombb, gh1f, bih1, bhh1, h1f,
                                              H2f + (size_t)t * B_ * H_,
                                              H2b + (size_t)t * B_ * H_);
  }

  // logit = tanh(H2 @ Who.T + bho) -> bf16
  gemm_bt<<<dim3(E_ / 64, NR_ / 64), 256, 0, stream>>>(H2b, whob, bho, nullptr, logitb,
                                                       NR_, E_, H_, 1);
  // streaming LSE over vocab
  k_lse<<<dim3(16, 16), 512, 0, stream>>>(logitb, wopb, bop, part);
  // finalize per-row nll
  k_final<<<dim3(8), 256, 0, stream>>>(part, logitb, Wop, bop, y, nllb);
  // deterministic sum
  k_reduce<<<dim3(1), 256, 0, stream>>>(nllb, (float*)d_out);
}